// Round 4
// baseline (664.763 us; speedup 1.0000x reference)
//
#include <hip/hip_runtime.h>
#include <cmath>

typedef _Float16 f16;
typedef f16 f16x8 __attribute__((ext_vector_type(8)));
typedef f16 f16x4 __attribute__((ext_vector_type(4)));
typedef float f32x4 __attribute__((ext_vector_type(4)));

#define Ln 4096
#define Dn 256
#define NEGV (-1e30f)

// workspace byte offsets
#define B_QH   0ul           // fp16 Q = 16MB (dead after flash)
#define B_KH   (16ul << 20)  // fp16 K = 16MB (dead after flash)
#define B_VT   (32ul << 20)  // fp16 V^T [8][256][4096] = 16MB (dead after flash)
#define B_ATH  (48ul << 20)  // fp16 attn = 16MB
#define B_T    0ul           // fp32 t = 32MB, overlays QH+KH (dead by then)
#define B_LENS (64ul << 20)  // lens[8]
#define B_SUMS (B_LENS + 128)         // 512 floats
#define B_WQT  (B_LENS + 4096)        // fp16 WqT [256n][256k] = 128KB
#define B_WKT  (B_WQT + (128ul<<10))
#define B_WVT  (B_WKT + (128ul<<10))
#define B_WTT  (B_WVT + (128ul<<10))

__device__ __forceinline__ void async_ld16(f16* lds, const f16* g) {
  __builtin_amdgcn_global_load_lds((const __attribute__((address_space(1))) unsigned int*)g,
                                   (__attribute__((address_space(3))) unsigned int*)lds, 16, 0, 0);
}

__global__ __launch_bounds__(256) void k_init(const int* __restrict__ mask, int* __restrict__ lens,
                                              float* __restrict__ sums) {
  const int b = blockIdx.x, tid = threadIdx.x;
  if (b == 0) { sums[tid] = 0.f; sums[256 + tid] = 0.f; }
  int cnt = 0;
  for (int l = tid; l < Ln; l += 256) cnt += (mask[b * Ln + l] != 0) ? 1 : 0;
  __shared__ int red[256];
  red[tid] = cnt;
  __syncthreads();
  for (int s = 128; s > 0; s >>= 1) {
    if (tid < s) red[tid] += red[tid + s];
    __syncthreads();
  }
  if (tid == 0) lens[b] = red[0];
}

// transpose+cast weights: WT[n][k] = (f16)W[k][n]
__global__ __launch_bounds__(256) void k_cast_w(const float* __restrict__ W0, const float* __restrict__ W1,
                                                const float* __restrict__ W2, const float* __restrict__ W3,
                                                f16* __restrict__ T0, f16* __restrict__ T1,
                                                f16* __restrict__ T2, f16* __restrict__ T3) {
  const float* Ws[4] = {W0, W1, W2, W3};
  f16* Ts[4] = {T0, T1, T2, T3};
  const float* W = Ws[blockIdx.x];
  f16* T = Ts[blockIdx.x];
  const int k0 = blockIdx.y * 64, n0 = blockIdx.z * 64;
  const int tid = threadIdx.x;
  __shared__ float ld[64][65];
#pragma unroll
  for (int i = 0; i < 16; ++i) {
    int flat = i * 256 + tid;
    int r = flat >> 6, c = flat & 63;
    ld[r][c] = W[(size_t)(k0 + r) * Dn + n0 + c];
  }
  __syncthreads();
#pragma unroll
  for (int i = 0; i < 16; ++i) {
    int flat = i * 256 + tid;
    int r = flat >> 6, c = flat & 63;
    T[(size_t)(n0 + r) * Dn + k0 + c] = (f16)ld[c][r];
  }
}

// Fused x-cast + QKV projection. A staged fp32->fp16 into swizzled LDS; B frags from L2 W^T.
__global__ __launch_bounds__(256) void k_qkv(const float* __restrict__ x, const f16* __restrict__ WqT,
                                             const f16* __restrict__ WkT, const f16* __restrict__ WvT,
                                             f16* __restrict__ Qh, f16* __restrict__ Kh,
                                             f16* __restrict__ Vt) {
  __shared__ f16 sA[64 * 256];
  __shared__ f16 vts[256 * 72];
  const int tid = threadIdx.x;
  const int lane = tid & 63;
  const int ln15 = lane & 15;
  const int quad = lane >> 4;
  const int wave = tid >> 6;
  const int wr = wave >> 1;
  const int wn = wave & 1;
  const size_t row0 = (size_t)blockIdx.x * 64;

  {
    const float* src = x + row0 * Dn;
#pragma unroll
    for (int i = 0; i < 8; ++i) {
      int flat = i * 256 + tid;
      int r = flat >> 5, p = flat & 31, g = p ^ (r & 7);
      float4 lo = *(const float4*)&src[r * Dn + g * 8];
      float4 hi = *(const float4*)&src[r * Dn + g * 8 + 4];
      f16x8 h = {(f16)lo.x, (f16)lo.y, (f16)lo.z, (f16)lo.w,
                 (f16)hi.x, (f16)hi.y, (f16)hi.z, (f16)hi.w};
      *(f16x8*)&sA[flat * 8] = h;
    }
  }
  __syncthreads();

  f16x8 af[2][8];
#pragma unroll
  for (int rg = 0; rg < 2; ++rg) {
    int r = wr * 32 + rg * 16 + ln15;
    int sw = r & 7;
#pragma unroll
    for (int c = 0; c < 8; ++c)
      af[rg][c] = *(const f16x8*)&sA[r * 256 + (((c * 4 + quad) ^ sw) << 3)];
  }

  const f16* Bm[3] = {WqT, WkT, WvT};
  for (int m = 0; m < 3; ++m) {
    const f16* B = Bm[m];
    f32x4 acc0[8], acc1[8];
#pragma unroll
    for (int nt = 0; nt < 8; ++nt) {
#pragma unroll
      for (int i = 0; i < 4; ++i) { acc0[nt][i] = 0.f; acc1[nt][i] = 0.f; }
    }
#pragma unroll
    for (int c = 0; c < 8; ++c) {
#pragma unroll
      for (int nt = 0; nt < 8; ++nt) {
        f16x8 bf = *(const f16x8*)&B[(size_t)(wn * 128 + nt * 16 + ln15) * 256 + c * 32 + quad * 8];
        acc0[nt] = __builtin_amdgcn_mfma_f32_16x16x32_f16(af[0][c], bf, acc0[nt], 0, 0, 0);
        acc1[nt] = __builtin_amdgcn_mfma_f32_16x16x32_f16(af[1][c], bf, acc1[nt], 0, 0, 0);
      }
    }
    if (m < 2) {
      f16* dst = (m == 0) ? Qh : Kh;
#pragma unroll
      for (int nt = 0; nt < 8; ++nt) {
        int col = wn * 128 + nt * 16 + ln15;
#pragma unroll
        for (int i = 0; i < 4; ++i) {
          dst[(row0 + wr * 32 + quad * 4 + i) * (size_t)Dn + col] = (f16)acc0[nt][i];
          dst[(row0 + wr * 32 + 16 + quad * 4 + i) * (size_t)Dn + col] = (f16)acc1[nt][i];
        }
      }
    } else {
#pragma unroll
      for (int nt = 0; nt < 8; ++nt) {
        int ch = wn * 128 + nt * 16 + ln15;
#pragma unroll
        for (int i = 0; i < 4; ++i) {
          vts[ch * 72 + wr * 32 + quad * 4 + i] = (f16)acc0[nt][i];
          vts[ch * 72 + wr * 32 + 16 + quad * 4 + i] = (f16)acc1[nt][i];
        }
      }
      __syncthreads();
      const int b = (int)(row0 >> 12);
      const int l0 = (int)(row0 & 4095);
      f16* vdst = Vt + (size_t)b * Dn * Ln + (size_t)tid * Ln + l0;
#pragma unroll
      for (int j = 0; j < 8; ++j)
        *(f16x8*)(vdst + 8 * j) = *(const f16x8*)&vts[tid * 72 + 8 * j];
    }
  }
}

// Flash attention v2: 64q/block, 2 waves x 32q, 32-key double-buffered tiles, 1 barrier/tile,
// within-wave softmax, wave-private P round-trip, ballot-gated O rescale.
__global__ __launch_bounds__(128, 1) void k_flash(const f16* __restrict__ Qh, const f16* __restrict__ Kh,
                                                  const f16* __restrict__ Vt, const int* __restrict__ lens,
                                                  f16* __restrict__ attn) {
  const int b = blockIdx.y;
  const int len = lens[b];
  const int i0 = blockIdx.x * 64;
  if (i0 >= len) return;
  const int tid = threadIdx.x;   // 0..127
  const int lane = tid & 63;
  const int ln15 = lane & 15;
  const int quad = lane >> 4;
  const int w = tid >> 6;        // wave 0..1

  __shared__ f16 sK[2][32 * 256];   // 2 x 16KB, XOR-swizzled granules
  __shared__ f16 sV[2][256 * 32];   // 2 x 16KB, V^T [ch][key], swizzled
  __shared__ f16 sP[2][2][16 * 40]; // wave-private P tiles (16q x 32k, stride 40)

  const f16* Qb = Qh + (size_t)b * Ln * Dn;
  const f16* Kb = Kh + (size_t)b * Ln * Dn;
  const f16* Vb = Vt + (size_t)b * Dn * Ln;
  f16* Ab = attn + (size_t)b * Ln * Dn;

  // Q A-fragments for this wave's 2 q-tiles (rows w*32 + qt*16 + ln15)
  f16x8 qf[2][8];
#pragma unroll
  for (int qt = 0; qt < 2; ++qt) {
    const f16* qrow = Qb + (size_t)(i0 + w * 32 + qt * 16 + ln15) * Dn + quad * 8;
#pragma unroll
    for (int c = 0; c < 8; ++c) qf[qt][c] = *(const f16x8*)(qrow + c * 32);
  }

  f32x4 oAcc[2][16];
#pragma unroll
  for (int qt = 0; qt < 2; ++qt)
#pragma unroll
    for (int nf = 0; nf < 16; ++nf) { oAcc[qt][nf][0] = 0.f; oAcc[qt][nf][1] = 0.f; oAcc[qt][nf][2] = 0.f; oAcc[qt][nf][3] = 0.f; }
  float m_i[2][4], l_i[2][4];
#pragma unroll
  for (int qt = 0; qt < 2; ++qt)
#pragma unroll
    for (int i = 0; i < 4; ++i) { m_i[qt][i] = -INFINITY; l_i[qt][i] = 0.f; }

  const int T = (len + 31) >> 5;

  // stage tile 0 into buf 0
  {
#pragma unroll
    for (int i = 0; i < 8; ++i) {
      int flat = i * 128 + tid;
      int r = flat >> 5, p = flat & 31, g = p ^ (r & 7);
      async_ld16(&sK[0][(i * 128 + (tid & 64)) * 8], Kb + (size_t)r * Dn + g * 8);
    }
#pragma unroll
    for (int i = 0; i < 8; ++i) {
      int flat = i * 128 + tid;
      int r = flat >> 2, p = flat & 3, g = p ^ (r & 3);
      async_ld16(&sV[0][(i * 128 + (tid & 64)) * 8], Vb + (size_t)r * Ln + g * 8);
    }
  }

  for (int t = 0; t < T; ++t) {
    const int buf = t & 1;
    __syncthreads();  // stage(t) visible to all; all waves done computing on buf^1
    if (t + 1 < T) {
      const int j1 = (t + 1) << 5;
#pragma unroll
      for (int i = 0; i < 8; ++i) {
        int flat = i * 128 + tid;
        int r = flat >> 5, p = flat & 31, g = p ^ (r & 7);
        async_ld16(&sK[buf ^ 1][(i * 128 + (tid & 64)) * 8], Kb + (size_t)(j1 + r) * Dn + g * 8);
      }
#pragma unroll
      for (int i = 0; i < 8; ++i) {
        int flat = i * 128 + tid;
        int r = flat >> 2, p = flat & 3, g = p ^ (r & 3);
        async_ld16(&sV[buf ^ 1][(i * 128 + (tid & 64)) * 8], Vb + (size_t)r * Ln + j1 + g * 8);
      }
    }

    // ---- S = Q K^T on buf ----
    f32x4 s[2][2];
#pragma unroll
    for (int qt = 0; qt < 2; ++qt)
#pragma unroll
      for (int kt = 0; kt < 2; ++kt) { s[qt][kt][0] = 0.f; s[qt][kt][1] = 0.f; s[qt][kt][2] = 0.f; s[qt][kt][3] = 0.f; }
    const int sw = ln15 & 7;
#pragma unroll
    for (int c = 0; c < 8; ++c) {
      int gk = (((c * 4 + quad) ^ sw) << 3);
      f16x8 b0 = *(const f16x8*)&sK[buf][ln15 * 256 + gk];
      f16x8 b1 = *(const f16x8*)&sK[buf][(16 + ln15) * 256 + gk];
      s[0][0] = __builtin_amdgcn_mfma_f32_16x16x32_f16(qf[0][c], b0, s[0][0], 0, 0, 0);
      s[0][1] = __builtin_amdgcn_mfma_f32_16x16x32_f16(qf[0][c], b1, s[0][1], 0, 0, 0);
      s[1][0] = __builtin_amdgcn_mfma_f32_16x16x32_f16(qf[1][c], b0, s[1][0], 0, 0, 0);
      s[1][1] = __builtin_amdgcn_mfma_f32_16x16x32_f16(qf[1][c], b1, s[1][1], 0, 0, 0);
    }

    // ---- online softmax (within-wave) ----
    const int j0 = t << 5;
    const bool iv0 = (j0 + ln15) >= len;
    const bool iv1 = (j0 + 16 + ln15) >= len;
    float alpha[2][4];
    bool need = false;
#pragma unroll
    for (int qt = 0; qt < 2; ++qt) {
#pragma unroll
      for (int i = 0; i < 4; ++i) {
        float a0 = iv0 ? NEGV : s[qt][0][i];
        float a1 = iv1 ? NEGV : s[qt][1][i];
        float rm = fmaxf(a0, a1);
        rm = fmaxf(rm, __shfl_xor(rm, 1));
        rm = fmaxf(rm, __shfl_xor(rm, 2));
        rm = fmaxf(rm, __shfl_xor(rm, 4));
        rm = fmaxf(rm, __shfl_xor(rm, 8));
        float mo = m_i[qt][i];
        float mn = fmaxf(mo, rm);
        float al = __expf(mo - mn);
        float p0 = __expf(a0 - mn);
        float p1 = __expf(a1 - mn);
        float rs = p0 + p1;
        rs += __shfl_xor(rs, 1);
        rs += __shfl_xor(rs, 2);
        rs += __shfl_xor(rs, 4);
        rs += __shfl_xor(rs, 8);
        l_i[qt][i] = l_i[qt][i] * al + rs;
        m_i[qt][i] = mn;
        alpha[qt][i] = al;
        need |= (al < 1.0f);
        sP[w][qt][(quad * 4 + i) * 40 + ln15] = (f16)p0;
        sP[w][qt][(quad * 4 + i) * 40 + 16 + ln15] = (f16)p1;
      }
    }
    if (__any(need ? 1 : 0)) {
#pragma unroll
      for (int qt = 0; qt < 2; ++qt)
#pragma unroll
        for (int nf = 0; nf < 16; ++nf)
#pragma unroll
          for (int i = 0; i < 4; ++i) oAcc[qt][nf][i] *= alpha[qt][i];
    }

    // ---- PV on buf ----
    f16x8 pa0 = *(const f16x8*)&sP[w][0][ln15 * 40 + quad * 8];
    f16x8 pa1 = *(const f16x8*)&sP[w][1][ln15 * 40 + quad * 8];
#pragma unroll
    for (int nf = 0; nf < 16; ++nf) {
      int rv = nf * 16 + ln15;
      f16x8 vb = *(const f16x8*)&sV[buf][rv * 32 + ((quad ^ (ln15 & 3)) << 3)];
      oAcc[0][nf] = __builtin_amdgcn_mfma_f32_16x16x32_f16(pa0, vb, oAcc[0][nf], 0, 0, 0);
      oAcc[1][nf] = __builtin_amdgcn_mfma_f32_16x16x32_f16(pa1, vb, oAcc[1][nf], 0, 0, 0);
    }
  }

#pragma unroll
  for (int qt = 0; qt < 2; ++qt) {
#pragma unroll
    for (int i = 0; i < 4; ++i) {
      int row = i0 + w * 32 + qt * 16 + quad * 4 + i;
      if (row < len) {
        float inv = 1.f / l_i[qt][i];
#pragma unroll
        for (int nf = 0; nf < 16; ++nf)
          Ab[(size_t)row * Dn + nf * 16 + ln15] = (f16)(oAcc[qt][nf][i] * inv);
      }
    }
  }
}

// t = attn @ Wt with fused masked BN statistics (sum, sum-sq per channel)
__global__ __launch_bounds__(256) void k_t(const f16* __restrict__ ah, const f16* __restrict__ WtT,
                                           const int* __restrict__ mask, float* __restrict__ t,
                                           float* __restrict__ sums) {
  __shared__ f16 sA[64 * 256];
  __shared__ float sSum[256];
  __shared__ float sSq[256];
  const int tid = threadIdx.x;
  const int lane = tid & 63;
  const int ln15 = lane & 15;
  const int quad = lane >> 4;
  const int wave = tid >> 6;
  const int wr = wave >> 1;
  const int wn = wave & 1;
  const size_t row0 = (size_t)blockIdx.x * 64;
  sSum[tid] = 0.f;
  sSq[tid] = 0.f;
  {
    const f16* src = ah + row0 * Dn;
#pragma unroll
    for (int i = 0; i < 8; ++i) {
      int flat = i * 256 + tid;
      int r = flat >> 5, p = flat & 31, g = p ^ (r & 7);
      async_ld16(&sA[(i * 256 + (tid & 192)) * 8], src + r * 256 + g * 8);
    }
  }
  __syncthreads();
  f16x8 af[2][8];
#pragma unroll
  for (int rg = 0; rg < 2; ++rg) {
    int r = wr * 32 + rg * 16 + ln15;
    int sw = r & 7;
#pragma unroll
    for (int c = 0; c < 8; ++c)
      af[rg][c] = *(const f16x8*)&sA[r * 256 + (((c * 4 + quad) ^ sw) << 3)];
  }
  f32x4 acc0[8], acc1[8];
#pragma unroll
  for (int nt = 0; nt < 8; ++nt) {
#pragma unroll
    for (int i = 0; i < 4; ++i) { acc0[nt][i] = 0.f; acc1[nt][i] = 0.f; }
  }
#pragma unroll
  for (int c = 0; c < 8; ++c) {
#pragma unroll
    for (int nt = 0; nt < 8; ++nt) {
      f16x8 bf = *(const f16x8*)&WtT[(size_t)(wn * 128 + nt * 16 + ln15) * 256 + c * 32 + quad * 8];
      acc0[nt] = __builtin_amdgcn_mfma_f32_16x16x32_f16(af[0][c], bf, acc0[nt], 0, 0, 0);
      acc1[nt] = __builtin_amdgcn_mfma_f32_16x16x32_f16(af[1][c], bf, acc1[nt], 0, 0, 0);
    }
  }
  // store t + masked per-channel partial sums
  float msk0[4], msk1[4];
#pragma unroll
  for (int i = 0; i < 4; ++i) {
    size_t r = row0 + wr * 32 + quad * 4 + i;
    msk0[i] = (mask[r] != 0) ? 1.f : 0.f;
    msk1[i] = (mask[r + 16] != 0) ? 1.f : 0.f;
  }
#pragma unroll
  for (int nt = 0; nt < 8; ++nt) {
    int col = wn * 128 + nt * 16 + ln15;
    float ps = 0.f, pq = 0.f;
#pragma unroll
    for (int i = 0; i < 4; ++i) {
      float v0 = acc0[nt][i], v1 = acc1[nt][i];
      t[(row0 + wr * 32 + quad * 4 + i) * (size_t)Dn + col] = v0;
      t[(row0 + wr * 32 + 16 + quad * 4 + i) * (size_t)Dn + col] = v1;
      ps += v0 * msk0[i] + v1 * msk1[i];
      pq += v0 * v0 * msk0[i] + v1 * v1 * msk1[i];
    }
    ps += __shfl_xor(ps, 16); ps += __shfl_xor(ps, 32);
    pq += __shfl_xor(pq, 16); pq += __shfl_xor(pq, 32);
    if (quad == 0) {
      atomicAdd(&sSum[col], ps);
      atomicAdd(&sSq[col], pq);
    }
  }
  __syncthreads();
  atomicAdd(&sums[tid], sSum[tid]);
  atomicAdd(&sums[256 + tid], sSq[tid]);
}

__device__ __forceinline__ float bn_relu(float tv, int ch, float fn, const float* sums,
                                         const float* gamma, const float* beta) {
  float mean = sums[ch] / fn;
  float var = sums[256 + ch] / fn - mean * mean;
  float y = gamma[ch] * (tv - mean) * rsqrtf(var + 1e-4f) + beta[ch];
  return y > 0.f ? y : 0.f;
}

__global__ __launch_bounds__(256) void k_final(const float* __restrict__ x, const int* __restrict__ mask,
                                               const float* __restrict__ t, const float* __restrict__ gamma,
                                               const float* __restrict__ beta, const float* __restrict__ sums,
                                               const int* __restrict__ lens, float* __restrict__ out) {
  const size_t idx = (size_t)blockIdx.x * 256 + threadIdx.x;
  const size_t row = idx >> 6;
  const int c = (int)(idx & 63) * 4;
  float4 o;
  if (mask[row] == 0) {
    o = make_float4(0.f, 0.f, 0.f, 0.f);
  } else {
    int n = 0;
#pragma unroll
    for (int i = 0; i < 8; ++i) n += lens[i];
    const float fn = (float)n;
    float4 tv = *(const float4*)&t[row * Dn + c];
    float4 xv = *(const float4*)&x[row * Dn + c];
    o.x = xv.x + bn_relu(tv.x, c + 0, fn, sums, gamma, beta);
    o.y = xv.y + bn_relu(tv.y, c + 1, fn, sums, gamma, beta);
    o.z = xv.z + bn_relu(tv.z, c + 2, fn, sums, gamma, beta);
    o.w = xv.w + bn_relu(tv.w, c + 3, fn, sums, gamma, beta);
  }
  *(float4*)&out[idx * 4] = o;
}

extern "C" void kernel_launch(void* const* d_in, const int* in_sizes, int n_in,
                              void* d_out, int out_size, void* d_ws, size_t ws_size,
                              hipStream_t stream) {
  const float* x = (const float*)d_in[0];
  const int* mask = (const int*)d_in[1];
  const float* Wq = (const float*)d_in[2];
  const float* Wk = (const float*)d_in[3];
  const float* Wv = (const float*)d_in[4];
  const float* Wt = (const float*)d_in[5];
  const float* gamma = (const float*)d_in[6];
  const float* beta = (const float*)d_in[7];
  float* out = (float*)d_out;
  char* wsb = (char*)d_ws;

  f16* Qh = (f16*)(wsb + B_QH);
  f16* Kh = (f16*)(wsb + B_KH);
  f16* Vt = (f16*)(wsb + B_VT);
  f16* ath = (f16*)(wsb + B_ATH);
  float* t = (float*)(wsb + B_T);
  int* lens = (int*)(wsb + B_LENS);
  float* sums = (float*)(wsb + B_SUMS);
  f16* WqT = (f16*)(wsb + B_WQT);
  f16* WkT = (f16*)(wsb + B_WKT);
  f16* WvT = (f16*)(wsb + B_WVT);
  f16* WtT = (f16*)(wsb + B_WTT);

  k_init<<<8, 256, 0, stream>>>(mask, lens, sums);
  k_cast_w<<<dim3(4, 4, 4), 256, 0, stream>>>(Wq, Wk, Wv, Wt, WqT, WkT, WvT, WtT);
  k_qkv<<<512, 256, 0, stream>>>(x, WqT, WkT, WvT, Qh, Kh, Vt);
  k_flash<<<dim3(64, 8), 128, 0, stream>>>(Qh, Kh, Vt, lens, ath);
  k_t<<<512, 256, 0, stream>>>(ath, WtT, mask, t, sums);   // t overlays Qh/Kh (dead)
  k_final<<<8192, 256, 0, stream>>>(x, mask, t, gamma, beta, sums, lens, out);
}